// Round 8
// baseline (284.212 us; speedup 1.0000x reference)
//
#include <hip/hip_runtime.h>

// RNMF encoder, MI355X. Identities:
//   b_k = b_0 + H z_k  (ISTA scan telescopes) => z <- relu(b0 + H z - t), 16x
//   H z = [(1-0.1*eta) z_q - eta*D^T(u+z_m) ; (1-1.1*eta) z_m - eta*u], u = D z_q
// eta = 1/lambda_max(D^T D) via on-device power method (G^8 squarings + 28 iters).
// History: R3 2x2-tile 120us; R4 spill(cap 64); R5 pair-blocks flat; R6 one-
//   barrier flat; R7 C-in/prescale spilled; R8 split prep -> total-main ~104us
//   CONSTANT (harness+prep floor). R9 4-way row-split waves (VGPR 80): 109.5us,
//   occupancy 20->30% == the (256,3) bound exactly; TLP gains real, sub-linear.
// R10: one line — launch_bounds (256,3)->(256,4). At VGPR=80 the occupancy
//   quantum (waves/SIMD steps at 64/128/256) allows 4 blocks/CU; LDS 4x16.9KB
//   fits. Cap 128 >> 80, no R4-style spill risk. 4 blocks/CU is this
//   decomposition's structural TLP ceiling (>4 needs VGPR<=64, impossible:
//   D-frags alone are 64).

typedef __bf16 bf16x8 __attribute__((ext_vector_type(8)));
typedef float f32x4 __attribute__((ext_vector_type(4)));
typedef float f32x2 __attribute__((ext_vector_type(2)));

#define MFMA16(a, b, c) __builtin_amdgcn_mfma_f32_16x16x32_bf16((a), (b), (c), 0, 0, 0)

#define NTOT 65536
#define NCOL 16

__device__ __forceinline__ unsigned pk2(float a, float b) {
#if __has_builtin(__builtin_amdgcn_cvt_pk_bf16_f32)
  return __builtin_bit_cast(unsigned, __builtin_amdgcn_cvt_pk_bf16_f32(a, b));
#else
  unsigned short ua = __builtin_bit_cast(unsigned short, (__bf16)a);
  unsigned short ub = __builtin_bit_cast(unsigned short, (__bf16)b);
  return (unsigned)ua | ((unsigned)ub << 16);
#endif
}
__device__ __forceinline__ unsigned pk2v(f32x2 v) { return pk2(v[0], v[1]); }
__device__ __forceinline__ f32x2 f2(float s) { f32x2 v = {s, s}; return v; }
__device__ __forceinline__ f32x2 pfma(f32x2 a, f32x2 b, f32x2 c) {
  return __builtin_elementwise_fma(a, b, c);
}
__device__ __forceinline__ f32x2 pmax0(f32x2 a) {
  return __builtin_elementwise_max(a, f2(0.f));
}

// ---------------- Kernel 0: prep (3 blocks, 256 threads) ----------------
// ws: [0..255] header (wsf[0]=eta), +256: Dbf [256][64] bf16, +256+32768: DTbf [64][256] bf16.
// block 0: eta pipeline; blocks 1,2: stage Dbf + DTbf (no LDS/barriers).
#define GOF(row) ((row) * 68 + (((row) >> 3) << 2))   // skewed fp32 row offset (16B-aligned)
__global__ void rnmf_prep(const float* __restrict__ D, void* __restrict__ ws) {
  float* wsf = (float*)ws;
  __bf16* Dbf = (__bf16*)((char*)ws + 256);
  __bf16* DTbf = (__bf16*)((char*)ws + 256 + 32768);

  const int tid = threadIdx.x;

  if (blockIdx.x != 0) {
    const int bs = blockIdx.x - 1;   // 0 or 1
#pragma unroll
    for (int e = 0; e < 8; ++e) {
      int i4 = bs * 2048 + e * 256 + tid;
      float4 dv = *(const float4*)(D + i4 * 4);
      uint2 u; u.x = pk2(dv.x, dv.y); u.y = pk2(dv.z, dv.w);
      *(uint2*)(Dbf + i4 * 4) = u;
    }
    const int a = tid & 63;
#pragma unroll
    for (int e = 0; e < 4; ++e) {
      int kc = bs * 16 + e * 4 + (tid >> 6);   // 32 k-chunks of 8
      int k0 = kc * 8;
      float g0 = D[(k0 + 0) * 64 + a], g1 = D[(k0 + 1) * 64 + a];
      float g2 = D[(k0 + 2) * 64 + a], g3 = D[(k0 + 3) * 64 + a];
      float g4 = D[(k0 + 4) * 64 + a], g5 = D[(k0 + 5) * 64 + a];
      float g6 = D[(k0 + 6) * 64 + a], g7 = D[(k0 + 7) * 64 + a];
      uint4 o;
      o.x = pk2(g0, g1); o.y = pk2(g2, g3); o.z = pk2(g4, g5); o.w = pk2(g6, g7);
      *(uint4*)(DTbf + a * 256 + k0) = o;
    }
    return;
  }

  // ---- block 0: eta pipeline ----
  __shared__ __bf16 DTl[64 * 264];   // D^T, [a][k] stride 264
  __shared__ __bf16 gA[64 * 72];
  __shared__ __bf16 gB[64 * 72];
  __shared__ float gf[64 * 68 + 32]; // G^8 fp32, skewed rows
  __shared__ __align__(16) float xv[64];

  const int w = tid >> 6, lane = tid & 63, c = lane & 15, q4 = lane >> 4;

#pragma unroll
  for (int e = 0; e < 64; ++e) {
    int flat = e * 256 + tid;
    int k = flat >> 6, a = flat & 63;
    DTl[a * 264 + k] = (__bf16)D[k * 64 + a];
  }
  __syncthreads();
  // G = D^T D
#pragma unroll
  for (int ct = 0; ct < 4; ++ct) {
    f32x4 acc = {0.f, 0.f, 0.f, 0.f};
#pragma unroll
    for (int kb = 0; kb < 8; ++kb) {
      bf16x8 a = *(const bf16x8*)&DTl[(16 * w + c) * 264 + 32 * kb + 8 * q4];
      bf16x8 b = *(const bf16x8*)&DTl[(16 * ct + c) * 264 + 32 * kb + 8 * q4];
      acc = MFMA16(a, b, acc);
    }
#pragma unroll
    for (int r = 0; r < 4; ++r)
      gA[(16 * w + 4 * q4 + r) * 72 + 16 * ct + c] = (__bf16)acc[r];
  }
  __syncthreads();
  // G2
#pragma unroll
  for (int ct = 0; ct < 4; ++ct) {
    f32x4 acc = {0.f, 0.f, 0.f, 0.f};
#pragma unroll
    for (int kb = 0; kb < 2; ++kb) {
      bf16x8 a = *(const bf16x8*)&gA[(16 * w + c) * 72 + 32 * kb + 8 * q4];
      bf16x8 b = *(const bf16x8*)&gA[(16 * ct + c) * 72 + 32 * kb + 8 * q4];
      acc = MFMA16(a, b, acc);
    }
#pragma unroll
    for (int r = 0; r < 4; ++r)
      gB[(16 * w + 4 * q4 + r) * 72 + 16 * ct + c] = (__bf16)acc[r];
  }
  __syncthreads();
  // G4
#pragma unroll
  for (int ct = 0; ct < 4; ++ct) {
    f32x4 acc = {0.f, 0.f, 0.f, 0.f};
#pragma unroll
    for (int kb = 0; kb < 2; ++kb) {
      bf16x8 a = *(const bf16x8*)&gB[(16 * w + c) * 72 + 32 * kb + 8 * q4];
      bf16x8 b = *(const bf16x8*)&gB[(16 * ct + c) * 72 + 32 * kb + 8 * q4];
      acc = MFMA16(a, b, acc);
    }
#pragma unroll
    for (int r = 0; r < 4; ++r)
      gA[(16 * w + 4 * q4 + r) * 72 + 16 * ct + c] = (__bf16)acc[r];
  }
  __syncthreads();
  // G8 -> fp32
#pragma unroll
  for (int ct = 0; ct < 4; ++ct) {
    f32x4 acc = {0.f, 0.f, 0.f, 0.f};
#pragma unroll
    for (int kb = 0; kb < 2; ++kb) {
      bf16x8 a = *(const bf16x8*)&gA[(16 * w + c) * 72 + 32 * kb + 8 * q4];
      bf16x8 b = *(const bf16x8*)&gA[(16 * ct + c) * 72 + 32 * kb + 8 * q4];
      acc = MFMA16(a, b, acc);
    }
#pragma unroll
    for (int r = 0; r < 4; ++r)
      gf[GOF(16 * w + 4 * q4 + r) + 16 * ct + c] = acc[r];
  }
  __syncthreads();

  if (w == 0) {
    float td = gf[GOF(lane) + lane];
#pragma unroll
    for (int off = 32; off; off >>= 1) td += __shfl_xor(td, off, 64);
    const float tr = td;
    const float itr = 1.f / tr;
    xv[lane] = 1.f;
    float nm = 1.f;
    const int rowoff = GOF(lane);
    for (int itp = 0; itp < 28; ++itp) {
      float a0 = 0.f, a1 = 0.f, a2 = 0.f, a3 = 0.f;
#pragma unroll
      for (int k = 0; k < 64; k += 16) {
        float4 ga = *(const float4*)&gf[rowoff + k];
        float4 xa = *(const float4*)&xv[k];
        float4 gb = *(const float4*)&gf[rowoff + k + 4];
        float4 xb = *(const float4*)&xv[k + 4];
        float4 gc = *(const float4*)&gf[rowoff + k + 8];
        float4 xc = *(const float4*)&xv[k + 8];
        float4 gd = *(const float4*)&gf[rowoff + k + 12];
        float4 xd = *(const float4*)&xv[k + 12];
        a0 = fmaf(ga.x, xa.x, a0); a0 = fmaf(ga.y, xa.y, a0);
        a0 = fmaf(ga.z, xa.z, a0); a0 = fmaf(ga.w, xa.w, a0);
        a1 = fmaf(gb.x, xb.x, a1); a1 = fmaf(gb.y, xb.y, a1);
        a1 = fmaf(gb.z, xb.z, a1); a1 = fmaf(gb.w, xb.w, a1);
        a2 = fmaf(gc.x, xc.x, a2); a2 = fmaf(gc.y, xc.y, a2);
        a2 = fmaf(gc.z, xc.z, a2); a2 = fmaf(gc.w, xc.w, a2);
        a3 = fmaf(gd.x, xd.x, a3); a3 = fmaf(gd.y, xd.y, a3);
        a3 = fmaf(gd.z, xd.z, a3); a3 = fmaf(gd.w, xd.w, a3);
      }
      float acc = (a0 + a1) + (a2 + a3);
      float y = acc * itr;
      float n2 = y * y;
#pragma unroll
      for (int off = 32; off; off >>= 1) n2 += __shfl_xor(n2, off, 64);
      nm = sqrtf(n2);
      xv[lane] = y / nm;
    }
    if (lane == 0) wsf[0] = 1.f / powf(nm * tr, 0.125f);  // eta = 1/alpha
  }
}

// ---------------- Kernel 1: main (4096 blocks x 256 thr, 16 cols/block) -----
// 4-way row-split waves. Wave w:
//   GEMM1: zm rows [64w, 64w+64)  x all 16 cols (d1[4][2], 8 MFMA/iter)
//   GEMM2: zq rows [16w, 16w+16)  x all 16 cols (d2[8],    8 MFMA/iter)
// LDS arena overlay:
//   phase A: xs = fp32 X tile [col][row], stride 260  (16640 B)
//   phase B: zqb [kb<2][1024] at +0 (2KB), vb [kb<8][1024] at +2048 (8KB)
__global__ __launch_bounds__(256, 4) void rnmf_main(const float* __restrict__ X,
                                                    float* __restrict__ Z,
                                                    const void* __restrict__ ws) {
  const float* wsf = (const float*)ws;
  const __bf16* Dbf = (const __bf16*)((const char*)ws + 256);
  const __bf16* DTbf = (const __bf16*)((const char*)ws + 256 + 32768);

  __shared__ __align__(16) char arena[16640];
  float* xs = (float*)arena;
  char* smem = arena;

  const int tid = threadIdx.x;
  const int w = tid >> 6;          // 0..3: row-quarter
  const int lane = tid & 63;
  const int c = lane & 15;
  const int q4 = lane >> 4;
  const int q4h = q4 >> 1, q4l = q4 & 1;
  const int j0 = blockIdx.x * NCOL;

  // stage X tile: coalesced float4 global loads, scalar LDS scatter (one-time)
#pragma unroll
  for (int e = 0; e < 4; ++e) {
    int idx = e * 256 + tid;                  // float4 id, 1024 total
    int row = idx >> 2, c4 = (idx & 3) * 4;
    float4 g = *(const float4*)(X + row * NTOT + j0 + c4);
    xs[(c4 + 0) * 260 + row] = g.x;
    xs[(c4 + 1) * 260 + row] = g.y;
    xs[(c4 + 2) * 260 + row] = g.z;
    xs[(c4 + 3) * 260 + row] = g.w;
  }

  const float eta = wsf[0];
  const f32x2 etav = f2(eta);
  const f32x2 metav = f2(-eta);
  const f32x2 cqv = f2(1.f - 0.1f * eta);
  const f32x2 cmv = f2(1.f - 1.1f * eta);
  const float tm = 0.1f * eta;

  // D fragments (iteration-invariant, register-resident)
  bf16x8 d1[4][2];   // GEMM1 A: D rows [64w..64w+64), K=64
#pragma unroll
  for (int rt = 0; rt < 4; ++rt)
#pragma unroll
    for (int kb = 0; kb < 2; ++kb)
      d1[rt][kb] = *(const bf16x8*)(Dbf + (64 * w + 16 * rt + c) * 64 + 32 * kb + 8 * q4);
  bf16x8 d2[8];      // GEMM2 A: D^T rows [16w..16w+16), K=256
#pragma unroll
  for (int kb = 0; kb < 8; ++kb)
    d2[kb] = *(const bf16x8*)(DTbf + (16 * w + c) * 256 + 32 * kb + 8 * q4);

  __syncthreads();   // xs staged

  // pack the 16-col stripe of x into B-fragments once (K=256)
  bf16x8 xb[8];
#pragma unroll
  for (int kb = 0; kb < 8; ++kb) {
    const float* p = &xs[c * 260 + 32 * kb + 8 * q4];
    float4 lo = *(const float4*)p;
    float4 hi = *(const float4*)(p + 4);
    uint4 packed = {pk2(lo.x, lo.y), pk2(lo.z, lo.w), pk2(hi.x, hi.y), pk2(hi.z, hi.w)};
    xb[kb] = __builtin_bit_cast(bf16x8, packed);
  }

  // b0_q = eta * D^T x (this wave's 16 zq rows); 2 independent 4-chains
  f32x2 bqt2[2];
  {
    f32x4 aA = {0.f, 0.f, 0.f, 0.f}, aB = {0.f, 0.f, 0.f, 0.f};
#pragma unroll
    for (int kb = 0; kb < 4; ++kb) aA = MFMA16(d2[kb], xb[kb], aA);
#pragma unroll
    for (int kb = 4; kb < 8; ++kb) aB = MFMA16(d2[kb], xb[kb], aB);
    f32x4 acc = aA + aB;
    f32x2 a0 = {acc[0], acc[1]}, a1 = {acc[2], acc[3]};
    bqt2[0] = etav * a0;   // t_q = 0
    bqt2[1] = etav * a1;
  }

  // b0_m - t_m = eta*x - tm (exact fp32)
  f32x2 bmt2[4][2];
#pragma unroll
  for (int rt = 0; rt < 4; ++rt) {
    const float* p = &xs[c * 260 + 64 * w + 16 * rt + 4 * q4];
    float4 v = *(const float4*)p;
    f32x2 x0 = {v.x, v.y}, x1 = {v.z, v.w};
    bmt2[rt][0] = pfma(etav, x0, f2(-tm));
    bmt2[rt][1] = pfma(etav, x1, f2(-tm));
  }

  __syncthreads();   // xs dead -> arena reusable as zqb/vb

  // z1 = relu(b0 - t)
  f32x2 zq2[2], zm2[4][2];
#pragma unroll
  for (int p = 0; p < 2; ++p) zq2[p] = pmax0(bqt2[p]);
#pragma unroll
  for (int rt = 0; rt < 4; ++rt)
#pragma unroll
    for (int p = 0; p < 2; ++p) zm2[rt][p] = pmax0(bmt2[rt][p]);

  // per-lane LDS byte offsets (B-frag layouts; reads are base + lane*16)
  const int rb = lane * 16;
  const int vrd = 2048 + rb;                                        // + kb*1024
  const int wzq = w * 512 + q4h * 256 + c * 16 + 8 * q4l;           // wave w = rt2 slot
  const int wvb = 2048 + w * 2048 + q4h * 256 + c * 16 + 8 * q4l;   // + rt*512

  // publish z1_q
  {
    uint2 u; u.x = pk2v(zq2[0]); u.y = pk2v(zq2[1]);
    *(uint2*)(smem + wzq) = u;
  }

  for (int it = 0; it < 15; ++it) {
    __syncthreads();   // zqb ready; vb free
    // GEMM1: U = D z_q ; z_m update ; publish V = u + z_m(old)
    // 2 ds_reads feed 8 MFMAs (B shared across the 4 row-tiles)
    bf16x8 bz0 = *(const bf16x8*)(smem + rb);
    bf16x8 bz1 = *(const bf16x8*)(smem + rb + 1024);
#pragma unroll
    for (int rt = 0; rt < 4; ++rt) {
      f32x4 acc = {0.f, 0.f, 0.f, 0.f};
      acc = MFMA16(d1[rt][0], bz0, acc);
      acc = MFMA16(d1[rt][1], bz1, acc);
      f32x2 u0 = {acc[0], acc[1]}, u1 = {acc[2], acc[3]};
      f32x2 z0 = zm2[rt][0], z1v = zm2[rt][1];
      f32x2 v0 = u0 + z0, v1 = u1 + z1v;
      f32x2 t0 = pfma(cmv, z0, bmt2[rt][0]);
      f32x2 t1 = pfma(cmv, z1v, bmt2[rt][1]);
      zm2[rt][0] = pmax0(pfma(metav, u0, t0));
      zm2[rt][1] = pmax0(pfma(metav, u1, t1));
      uint2 uu; uu.x = pk2v(v0); uu.y = pk2v(v1);
      *(uint2*)(smem + wvb + rt * 512) = uu;
    }
    __syncthreads();   // vb ready; zqb free
    // GEMM2: s = D^T V ; 8 ds_reads feed 8 MFMAs; 2 independent 4-chains
    f32x4 aA = {0.f, 0.f, 0.f, 0.f}, aB = {0.f, 0.f, 0.f, 0.f};
#pragma unroll
    for (int kb = 0; kb < 4; ++kb) {
      bf16x8 bv = *(const bf16x8*)(smem + vrd + kb * 1024);
      aA = MFMA16(d2[kb], bv, aA);
    }
#pragma unroll
    for (int kb = 4; kb < 8; ++kb) {
      bf16x8 bv = *(const bf16x8*)(smem + vrd + kb * 1024);
      aB = MFMA16(d2[kb], bv, aB);
    }
    f32x4 s = aA + aB;
    f32x2 s0 = {s[0], s[1]}, s1 = {s[2], s[3]};
    f32x2 t0 = pfma(cqv, zq2[0], bqt2[0]);
    f32x2 t1 = pfma(cqv, zq2[1], bqt2[1]);
    zq2[0] = pmax0(pfma(metav, s0, t0));
    zq2[1] = pmax0(pfma(metav, s1, t1));
    uint2 u; u.x = pk2v(zq2[0]); u.y = pk2v(zq2[1]);
    *(uint2*)(smem + wzq) = u;
  }

  // store Z: rows 0..63 = q-part, rows 64..319 = m-part
#pragma unroll
  for (int p = 0; p < 2; ++p)
#pragma unroll
    for (int e = 0; e < 2; ++e)
      Z[(16 * w + 4 * q4 + 2 * p + e) * NTOT + j0 + c] = zq2[p][e];
#pragma unroll
  for (int rt = 0; rt < 4; ++rt)
#pragma unroll
    for (int p = 0; p < 2; ++p)
#pragma unroll
      for (int e = 0; e < 2; ++e)
        Z[(64 + 64 * w + 16 * rt + 4 * q4 + 2 * p + e) * NTOT + j0 + c] = zm2[rt][p][e];
}

extern "C" void kernel_launch(void* const* d_in, const int* in_sizes, int n_in,
                              void* d_out, int out_size, void* d_ws, size_t ws_size,
                              hipStream_t stream) {
  const float* X = (const float*)d_in[0];
  const float* D = (const float*)d_in[1];
  float* Z = (float*)d_out;
  rnmf_prep<<<dim3(3), dim3(256), 0, stream>>>(D, d_ws);
  rnmf_main<<<dim3(NTOT / NCOL), dim3(256), 0, stream>>>(X, Z, d_ws);
}

// Round 9
// 215.680 us; speedup vs baseline: 1.3178x; 1.3178x over previous
//
#include <hip/hip_runtime.h>

// RNMF encoder, MI355X. Identities:
//   b_k = b_0 + H z_k  (ISTA telescopes) => z <- relu(b0 + H z - t), 16x
//   V = D z_q + z_m ;  z_m' = relu(bmt + (1-0.1eta) z_m - eta*V)
//   z_q' = relu(bqt + (1-0.1eta) z_q - eta*D^T V)    [cm+eta == cq fold]
// eta = 1/lambda_max(D^T D) via power method (G^8 squarings + 28 iters).
// History: R3 120us; R4/R10 launch_bounds spills (cap acts on UNIFIED arch+AGPR
//   footprint; R9's ~160/wave -> 12 waves/CU is the TLP ceiling); R5/R6 flat;
//   R7 spill (2x tile); R8: total-main ~104-107us constant = harness+prep floor.
//   R9 4-way row-split: 109.5us, VALUBusy 47.6% = top pipe.
// R11: VALU trim at constant registers. GEMM1 C-in=zm (MFMA emits V directly,
//   update via cq-fold); DTbf prescaled by -eta in prep block 0 (off critical
//   path, R7-validated numerics) + negated x-pack -> GEMM2 C-in=bqt kills the
//   per-iter t-fma. State as f32x4 so C-in needs no assembling movs.
//   ~40 -> ~30 pk-VALU/wave-iter; DS/MFMA/barriers unchanged.

typedef __bf16 bf16x8 __attribute__((ext_vector_type(8)));
typedef float f32x4 __attribute__((ext_vector_type(4)));

#define MFMA16(a, b, c) __builtin_amdgcn_mfma_f32_16x16x32_bf16((a), (b), (c), 0, 0, 0)

#define NTOT 65536
#define NCOL 16

__device__ __forceinline__ unsigned pk2(float a, float b) {
#if __has_builtin(__builtin_amdgcn_cvt_pk_bf16_f32)
  return __builtin_bit_cast(unsigned, __builtin_amdgcn_cvt_pk_bf16_f32(a, b));
#else
  unsigned short ua = __builtin_bit_cast(unsigned short, (__bf16)a);
  unsigned short ub = __builtin_bit_cast(unsigned short, (__bf16)b);
  return (unsigned)ua | ((unsigned)ub << 16);
#endif
}
__device__ __forceinline__ f32x4 f4(float s) { f32x4 v = {s, s, s, s}; return v; }
__device__ __forceinline__ f32x4 pfma4(f32x4 a, f32x4 b, f32x4 c) {
  return __builtin_elementwise_fma(a, b, c);
}
__device__ __forceinline__ f32x4 pmax04(f32x4 a) {
  return __builtin_elementwise_max(a, f4(0.f));
}

// ---------------- Kernel 0: prep (3 blocks, 256 threads) ----------------
// ws: [0..255] header (wsf[0]=eta), +256: Dbf [256][64] bf16 (unscaled),
//     +256+32768: DTbf [64][256] bf16 = (-eta)*D^T  (prescaled, block 0).
// block 0: eta pipeline + prescaled DTbf; blocks 1,2: Dbf staging halves.
#define GOF(row) ((row) * 68 + (((row) >> 3) << 2))   // skewed fp32 row offset (16B-aligned)
__global__ void rnmf_prep(const float* __restrict__ D, void* __restrict__ ws) {
  float* wsf = (float*)ws;
  __bf16* Dbf = (__bf16*)((char*)ws + 256);
  __bf16* DTbf = (__bf16*)((char*)ws + 256 + 32768);

  const int tid = threadIdx.x;

  if (blockIdx.x != 0) {
    const int bs = blockIdx.x - 1;   // 0 or 1: half of Dbf each
#pragma unroll
    for (int e = 0; e < 8; ++e) {
      int i4 = bs * 2048 + e * 256 + tid;
      float4 dv = *(const float4*)(D + i4 * 4);
      uint2 u; u.x = pk2(dv.x, dv.y); u.y = pk2(dv.z, dv.w);
      *(uint2*)(Dbf + i4 * 4) = u;
    }
    return;
  }

  // ---- block 0: eta pipeline + prescaled DTbf ----
  __shared__ __bf16 DTl[64 * 264];   // D^T, [a][k] stride 264
  __shared__ __bf16 gA[64 * 72];
  __shared__ __bf16 gB[64 * 72];
  __shared__ float gf[64 * 68 + 32]; // G^8 fp32, skewed rows
  __shared__ __align__(16) float xv[64];
  __shared__ float etas;

  const int w = tid >> 6, lane = tid & 63, c = lane & 15, q4 = lane >> 4;

#pragma unroll
  for (int e = 0; e < 64; ++e) {
    int flat = e * 256 + tid;
    int k = flat >> 6, a = flat & 63;
    DTl[a * 264 + k] = (__bf16)D[k * 64 + a];
  }
  __syncthreads();
  // G = D^T D
#pragma unroll
  for (int ct = 0; ct < 4; ++ct) {
    f32x4 acc = {0.f, 0.f, 0.f, 0.f};
#pragma unroll
    for (int kb = 0; kb < 8; ++kb) {
      bf16x8 a = *(const bf16x8*)&DTl[(16 * w + c) * 264 + 32 * kb + 8 * q4];
      bf16x8 b = *(const bf16x8*)&DTl[(16 * ct + c) * 264 + 32 * kb + 8 * q4];
      acc = MFMA16(a, b, acc);
    }
#pragma unroll
    for (int r = 0; r < 4; ++r)
      gA[(16 * w + 4 * q4 + r) * 72 + 16 * ct + c] = (__bf16)acc[r];
  }
  __syncthreads();
  // G2
#pragma unroll
  for (int ct = 0; ct < 4; ++ct) {
    f32x4 acc = {0.f, 0.f, 0.f, 0.f};
#pragma unroll
    for (int kb = 0; kb < 2; ++kb) {
      bf16x8 a = *(const bf16x8*)&gA[(16 * w + c) * 72 + 32 * kb + 8 * q4];
      bf16x8 b = *(const bf16x8*)&gA[(16 * ct + c) * 72 + 32 * kb + 8 * q4];
      acc = MFMA16(a, b, acc);
    }
#pragma unroll
    for (int r = 0; r < 4; ++r)
      gB[(16 * w + 4 * q4 + r) * 72 + 16 * ct + c] = (__bf16)acc[r];
  }
  __syncthreads();
  // G4
#pragma unroll
  for (int ct = 0; ct < 4; ++ct) {
    f32x4 acc = {0.f, 0.f, 0.f, 0.f};
#pragma unroll
    for (int kb = 0; kb < 2; ++kb) {
      bf16x8 a = *(const bf16x8*)&gB[(16 * w + c) * 72 + 32 * kb + 8 * q4];
      bf16x8 b = *(const bf16x8*)&gB[(16 * ct + c) * 72 + 32 * kb + 8 * q4];
      acc = MFMA16(a, b, acc);
    }
#pragma unroll
    for (int r = 0; r < 4; ++r)
      gA[(16 * w + 4 * q4 + r) * 72 + 16 * ct + c] = (__bf16)acc[r];
  }
  __syncthreads();
  // G8 -> fp32
#pragma unroll
  for (int ct = 0; ct < 4; ++ct) {
    f32x4 acc = {0.f, 0.f, 0.f, 0.f};
#pragma unroll
    for (int kb = 0; kb < 2; ++kb) {
      bf16x8 a = *(const bf16x8*)&gA[(16 * w + c) * 72 + 32 * kb + 8 * q4];
      bf16x8 b = *(const bf16x8*)&gA[(16 * ct + c) * 72 + 32 * kb + 8 * q4];
      acc = MFMA16(a, b, acc);
    }
#pragma unroll
    for (int r = 0; r < 4; ++r)
      gf[GOF(16 * w + 4 * q4 + r) + 16 * ct + c] = acc[r];
  }
  __syncthreads();

  if (w == 0) {
    float td = gf[GOF(lane) + lane];
#pragma unroll
    for (int off = 32; off; off >>= 1) td += __shfl_xor(td, off, 64);
    const float tr = td;
    const float itr = 1.f / tr;
    xv[lane] = 1.f;
    float nm = 1.f;
    const int rowoff = GOF(lane);
    for (int itp = 0; itp < 28; ++itp) {
      float a0 = 0.f, a1 = 0.f, a2 = 0.f, a3 = 0.f;
#pragma unroll
      for (int k = 0; k < 64; k += 16) {
        float4 ga = *(const float4*)&gf[rowoff + k];
        float4 xa = *(const float4*)&xv[k];
        float4 gb = *(const float4*)&gf[rowoff + k + 4];
        float4 xb = *(const float4*)&xv[k + 4];
        float4 gc = *(const float4*)&gf[rowoff + k + 8];
        float4 xc = *(const float4*)&xv[k + 8];
        float4 gd = *(const float4*)&gf[rowoff + k + 12];
        float4 xd = *(const float4*)&xv[k + 12];
        a0 = fmaf(ga.x, xa.x, a0); a0 = fmaf(ga.y, xa.y, a0);
        a0 = fmaf(ga.z, xa.z, a0); a0 = fmaf(ga.w, xa.w, a0);
        a1 = fmaf(gb.x, xb.x, a1); a1 = fmaf(gb.y, xb.y, a1);
        a1 = fmaf(gb.z, xb.z, a1); a1 = fmaf(gb.w, xb.w, a1);
        a2 = fmaf(gc.x, xc.x, a2); a2 = fmaf(gc.y, xc.y, a2);
        a2 = fmaf(gc.z, xc.z, a2); a2 = fmaf(gc.w, xc.w, a2);
        a3 = fmaf(gd.x, xd.x, a3); a3 = fmaf(gd.y, xd.y, a3);
        a3 = fmaf(gd.z, xd.z, a3); a3 = fmaf(gd.w, xd.w, a3);
      }
      float acc = (a0 + a1) + (a2 + a3);
      float y = acc * itr;
      float n2 = y * y;
#pragma unroll
      for (int off = 32; off; off >>= 1) n2 += __shfl_xor(n2, off, 64);
      nm = sqrtf(n2);
      xv[lane] = y / nm;
    }
    if (lane == 0) {
      float e = 1.f / powf(nm * tr, 0.125f);  // eta = 1/alpha
      wsf[0] = e;
      etas = e;
    }
  }
  __syncthreads();   // etas visible; DTl intact

  // DTbf = (-eta) * D^T, bf16 (prescaled for the main loop's GEMM2)
  const float msc = -etas;
#pragma unroll
  for (int e = 0; e < 8; ++e) {
    int fi = e * 256 + tid;
    int a2 = fi >> 5;
    int k2 = (fi * 8) & 255;
    const __bf16* src = &DTl[a2 * 264 + k2];
    uint4 o;
    o.x = pk2(msc * (float)src[0], msc * (float)src[1]);
    o.y = pk2(msc * (float)src[2], msc * (float)src[3]);
    o.z = pk2(msc * (float)src[4], msc * (float)src[5]);
    o.w = pk2(msc * (float)src[6], msc * (float)src[7]);
    *(uint4*)(DTbf + fi * 8) = o;
  }
}

// ---------------- Kernel 1: main (4096 blocks x 256 thr, 16 cols/block) -----
// 4-way row-split waves (R9 geometry). Wave w:
//   GEMM1: zm rows [64w, 64w+64)  x 16 cols; C-in = zm -> MFMA emits V
//   GEMM2: zq rows [16w, 16w+16)  x 16 cols; d2 = (-eta)D^T; C-in = bqt
// LDS arena overlay:
//   phase A: xs = fp32 X tile [col][row], stride 260  (16640 B)
//   phase B: zqb [kb<2][1024] at +0 (2KB), vb [kb<8][1024] at +2048 (8KB)
__global__ __launch_bounds__(256, 3) void rnmf_main(const float* __restrict__ X,
                                                    float* __restrict__ Z,
                                                    const void* __restrict__ ws) {
  const float* wsf = (const float*)ws;
  const __bf16* Dbf = (const __bf16*)((const char*)ws + 256);
  const __bf16* DTbf = (const __bf16*)((const char*)ws + 256 + 32768);

  __shared__ __align__(16) char arena[16640];
  float* xs = (float*)arena;
  char* smem = arena;

  const int tid = threadIdx.x;
  const int w = tid >> 6;          // 0..3: row-quarter
  const int lane = tid & 63;
  const int c = lane & 15;
  const int q4 = lane >> 4;
  const int q4h = q4 >> 1, q4l = q4 & 1;
  const int j0 = blockIdx.x * NCOL;

  // stage X tile: coalesced float4 global loads, scalar LDS scatter (one-time)
#pragma unroll
  for (int e = 0; e < 4; ++e) {
    int idx = e * 256 + tid;                  // float4 id, 1024 total
    int row = idx >> 2, c4 = (idx & 3) * 4;
    float4 g = *(const float4*)(X + row * NTOT + j0 + c4);
    xs[(c4 + 0) * 260 + row] = g.x;
    xs[(c4 + 1) * 260 + row] = g.y;
    xs[(c4 + 2) * 260 + row] = g.z;
    xs[(c4 + 3) * 260 + row] = g.w;
  }

  const float eta = wsf[0];
  const f32x4 etav = f4(eta);
  const f32x4 metav = f4(-eta);
  const f32x4 cqv = f4(1.f - 0.1f * eta);   // cm + eta == cq: one constant for both
  const float tm = 0.1f * eta;

  // D fragments (iteration-invariant, register-resident)
  bf16x8 d1[4][2];   // GEMM1 A: D rows [64w..64w+64), K=64 (unscaled)
#pragma unroll
  for (int rt = 0; rt < 4; ++rt)
#pragma unroll
    for (int kb = 0; kb < 2; ++kb)
      d1[rt][kb] = *(const bf16x8*)(Dbf + (64 * w + 16 * rt + c) * 64 + 32 * kb + 8 * q4);
  bf16x8 d2[8];      // GEMM2 A: (-eta)*D^T rows [16w..16w+16), K=256
#pragma unroll
  for (int kb = 0; kb < 8; ++kb)
    d2[kb] = *(const bf16x8*)(DTbf + (16 * w + c) * 256 + 32 * kb + 8 * q4);

  __syncthreads();   // xs staged

  // pack NEGATED x stripe (K=256): d2'*(-x) = eta*D^T x = bqt directly
  bf16x8 xbn[8];
#pragma unroll
  for (int kb = 0; kb < 8; ++kb) {
    const float* p = &xs[c * 260 + 32 * kb + 8 * q4];
    float4 lo = *(const float4*)p;
    float4 hi = *(const float4*)(p + 4);
    uint4 packed = {pk2(-lo.x, -lo.y), pk2(-lo.z, -lo.w), pk2(-hi.x, -hi.y), pk2(-hi.z, -hi.w)};
    xbn[kb] = __builtin_bit_cast(bf16x8, packed);
  }

  // bqt = eta * D^T x (this wave's 16 zq rows); 2 independent 4-chains
  f32x4 bqt4;
  {
    f32x4 aA = {0.f, 0.f, 0.f, 0.f}, aB = {0.f, 0.f, 0.f, 0.f};
#pragma unroll
    for (int kb = 0; kb < 4; ++kb) aA = MFMA16(d2[kb], xbn[kb], aA);
#pragma unroll
    for (int kb = 4; kb < 8; ++kb) aB = MFMA16(d2[kb], xbn[kb], aB);
    bqt4 = aA + aB;   // t_q = 0
  }

  // bmt = eta*x - tm (exact fp32); rows 4q4+0..3 match the MFMA C/D layout
  f32x4 bmt4[4];
#pragma unroll
  for (int rt = 0; rt < 4; ++rt) {
    const float* p = &xs[c * 260 + 64 * w + 16 * rt + 4 * q4];
    float4 v = *(const float4*)p;
    f32x4 x4 = {v.x, v.y, v.z, v.w};
    bmt4[rt] = pfma4(etav, x4, f4(-tm));
  }

  __syncthreads();   // xs dead -> arena reusable as zqb/vb

  // z1 = relu(b0 - t)
  f32x4 zq4 = pmax04(bqt4);
  f32x4 zm4[4];
#pragma unroll
  for (int rt = 0; rt < 4; ++rt) zm4[rt] = pmax04(bmt4[rt]);

  // per-lane LDS byte offsets (B-frag layouts; reads are base + lane*16)
  const int rb = lane * 16;
  const int vrd = 2048 + rb;                                        // + kb*1024
  const int wzq = w * 512 + q4h * 256 + c * 16 + 8 * q4l;           // wave w = rt2 slot
  const int wvb = 2048 + w * 2048 + q4h * 256 + c * 16 + 8 * q4l;   // + rt*512

  // publish z1_q
  {
    uint2 u; u.x = pk2(zq4[0], zq4[1]); u.y = pk2(zq4[2], zq4[3]);
    *(uint2*)(smem + wzq) = u;
  }

  for (int it = 0; it < 15; ++it) {
    __syncthreads();   // zqb ready; vb free
    // GEMM1: V = D z_q + z_m via C-in; zm' = relu(bmt + cq*zm - eta*V); publish V
    bf16x8 bz0 = *(const bf16x8*)(smem + rb);
    bf16x8 bz1 = *(const bf16x8*)(smem + rb + 1024);
#pragma unroll
    for (int rt = 0; rt < 4; ++rt) {
      f32x4 V = MFMA16(d1[rt][0], bz0, zm4[rt]);
      V = MFMA16(d1[rt][1], bz1, V);
      zm4[rt] = pmax04(pfma4(metav, V, pfma4(cqv, zm4[rt], bmt4[rt])));
      uint2 uu; uu.x = pk2(V[0], V[1]); uu.y = pk2(V[2], V[3]);
      *(uint2*)(smem + wvb + rt * 512) = uu;
    }
    __syncthreads();   // vb ready; zqb free
    // GEMM2: s = bqt - eta*D^T V via C-in (chain A seeded with bqt), 2x4 chains
    f32x4 aA = bqt4, aB = {0.f, 0.f, 0.f, 0.f};
#pragma unroll
    for (int kb = 0; kb < 4; ++kb) {
      bf16x8 bv = *(const bf16x8*)(smem + vrd + kb * 1024);
      aA = MFMA16(d2[kb], bv, aA);
    }
#pragma unroll
    for (int kb = 4; kb < 8; ++kb) {
      bf16x8 bv = *(const bf16x8*)(smem + vrd + kb * 1024);
      aB = MFMA16(d2[kb], bv, aB);
    }
    f32x4 s = aA + aB;
    zq4 = pmax04(pfma4(cqv, zq4, s));   // relu(cq*zq + bqt - eta*D^T V)
    uint2 u; u.x = pk2(zq4[0], zq4[1]); u.y = pk2(zq4[2], zq4[3]);
    *(uint2*)(smem + wzq) = u;
  }

  // store Z: rows 0..63 = q-part, rows 64..319 = m-part
#pragma unroll
  for (int j = 0; j < 4; ++j)
    Z[(16 * w + 4 * q4 + j) * NTOT + j0 + c] = zq4[j];
#pragma unroll
  for (int rt = 0; rt < 4; ++rt)
#pragma unroll
    for (int j = 0; j < 4; ++j)
      Z[(64 + 64 * w + 16 * rt + 4 * q4 + j) * NTOT + j0 + c] = zm4[rt][j];
}

extern "C" void kernel_launch(void* const* d_in, const int* in_sizes, int n_in,
                              void* d_out, int out_size, void* d_ws, size_t ws_size,
                              hipStream_t stream) {
  const float* X = (const float*)d_in[0];
  const float* D = (const float*)d_in[1];
  float* Z = (float*)d_out;
  rnmf_prep<<<dim3(3), dim3(256), 0, stream>>>(D, d_ws);
  rnmf_main<<<dim3(NTOT / NCOL), dim3(256), 0, stream>>>(X, Z, d_ws);
}